// Round 1
// baseline (1283.642 us; speedup 1.0000x reference)
//
#include <hip/hip_runtime.h>
#include <cmath>

// GCN 2-layer forward on MI355X.
// Pipeline: deg -> dinv -> gemm1(x@W1) -> init h1 (bias+selfloop) -> edge scatter (atomic)
//        -> gemm2(relu(h1)@W2) -> init out (bias+selfloop) -> edge scatter -> log_softmax in-place.

#define THREADS 256

__global__ void k_deg(const int* __restrict__ dst, int E, int* __restrict__ cnt) {
    int i = blockIdx.x * blockDim.x + threadIdx.x;
    if (i < E) atomicAdd(&cnt[dst[i]], 1);
}

__global__ void k_dinv(const int* __restrict__ cnt, int N, float* __restrict__ dinv) {
    int i = blockIdx.x * blockDim.x + threadIdx.x;
    if (i < N) dinv[i] = rsqrtf((float)(cnt[i] + 1));  // +1 self-loop; always > 0
}

// C[M x NC] = A[M x 128] @ W[128 x NC], optional relu on A load.
// Block: 256 threads, 64-row tile, W fully staged in LDS, 8-deep k chunks.
template <int NC, bool RELU>
__global__ __launch_bounds__(256) void k_gemm(const float* __restrict__ A,
                                              const float* __restrict__ W,
                                              float* __restrict__ Out, int M) {
    constexpr int CG  = NC / 4;               // col groups (4 cols each)
    constexpr int RPT = (64 * NC) / (256 * 4);// rows per thread (128->8, 64->4)
    __shared__ float Wl[128 * NC];
    __shared__ float xs[64][8];
    const int tid = threadIdx.x;
    const int tx = tid % CG;                  // col group
    const int ty = tid / CG;                  // row group
    const int row0 = blockIdx.x * 64;

    for (int idx = tid * 4; idx < 128 * NC; idx += 256 * 4)
        *(float4*)&Wl[idx] = *(const float4*)&W[idx];

    float acc[RPT][4];
#pragma unroll
    for (int i = 0; i < RPT; i++)
#pragma unroll
        for (int j = 0; j < 4; j++) acc[i][j] = 0.f;

    const int lrow = tid >> 2;        // 0..63
    const int lk = (tid & 3) * 2;     // 0,2,4,6

    for (int k0 = 0; k0 < 128; k0 += 8) {
        __syncthreads();              // also covers initial W staging
        const int grow = row0 + lrow;
        float2 v = make_float2(0.f, 0.f);
        if (grow < M) v = *(const float2*)&A[(size_t)grow * 128 + k0 + lk];
        if (RELU) { v.x = fmaxf(v.x, 0.f); v.y = fmaxf(v.y, 0.f); }
        xs[lrow][lk] = v.x;
        xs[lrow][lk + 1] = v.y;
        __syncthreads();
#pragma unroll
        for (int kk = 0; kk < 8; kk++) {
            float4 wv = *(float4*)&Wl[(k0 + kk) * NC + tx * 4];
#pragma unroll
            for (int i = 0; i < RPT; i++) {
                float a = xs[ty * RPT + i][kk];
                acc[i][0] += a * wv.x;
                acc[i][1] += a * wv.y;
                acc[i][2] += a * wv.z;
                acc[i][3] += a * wv.w;
            }
        }
    }
#pragma unroll
    for (int i = 0; i < RPT; i++) {
        const int row = row0 + ty * RPT + i;
        if (row < M)
            *(float4*)&Out[(size_t)row * NC + tx * 4] =
                make_float4(acc[i][0], acc[i][1], acc[i][2], acc[i][3]);
    }
}

// h[i][j] = b[j] + dinv[i]^2 * xw[i][j]   (bias + self-loop message)
template <int NC>
__global__ void k_init(const float* __restrict__ xw, const float* __restrict__ dinv,
                       const float* __restrict__ b, float* __restrict__ h, int N) {
    long idx = (long)blockIdx.x * blockDim.x + threadIdx.x;
    long total = (long)N * NC / 4;
    if (idx >= total) return;
    long p = idx * 4;
    int i = (int)(p / NC);
    int j = (int)(p % NC);
    float di = dinv[i];
    float w = di * di;
    float4 v = *(const float4*)&xw[p];
    float4 bb = *(const float4*)&b[j];
    *(float4*)&h[p] = make_float4(bb.x + w * v.x, bb.y + w * v.y,
                                  bb.z + w * v.z, bb.w + w * v.w);
}

// One wave per edge iteration: lane j covers columns. 128-wide variant.
__global__ void k_scat128(const int* __restrict__ src, const int* __restrict__ dst, int E,
                          const float* __restrict__ dinv, const float* __restrict__ xw,
                          float* __restrict__ h) {
    const int lane = threadIdx.x & 63;
    int wid = (blockIdx.x * blockDim.x + threadIdx.x) >> 6;
    const int nw = (gridDim.x * blockDim.x) >> 6;
    for (int e = wid; e < E; e += nw) {
        int s = src[e], d = dst[e];
        float w = dinv[s] * dinv[d];
        const float* row = xw + (size_t)s * 128;
        float v0 = row[lane];
        float v1 = row[lane + 64];
        float* orow = h + (size_t)d * 128;
        unsafeAtomicAdd(&orow[lane], w * v0);
        unsafeAtomicAdd(&orow[lane + 64], w * v1);
    }
}

__global__ void k_scat64(const int* __restrict__ src, const int* __restrict__ dst, int E,
                         const float* __restrict__ dinv, const float* __restrict__ xw,
                         float* __restrict__ h) {
    const int lane = threadIdx.x & 63;
    int wid = (blockIdx.x * blockDim.x + threadIdx.x) >> 6;
    const int nw = (gridDim.x * blockDim.x) >> 6;
    for (int e = wid; e < E; e += nw) {
        int s = src[e], d = dst[e];
        float w = dinv[s] * dinv[d];
        float v = xw[(size_t)s * 64 + lane];
        unsafeAtomicAdd(&h[(size_t)d * 64 + lane], w * v);
    }
}

// In-place log_softmax over 64 cols; one wave per row.
__global__ void k_lsm(float* __restrict__ out, int N) {
    const int lane = threadIdx.x & 63;
    const int row = (blockIdx.x * blockDim.x + threadIdx.x) >> 6;
    if (row >= N) return;
    float v = out[(size_t)row * 64 + lane];
    float m = v;
#pragma unroll
    for (int o = 32; o > 0; o >>= 1) m = fmaxf(m, __shfl_xor(m, o));
    float e = expf(v - m);
    float s = e;
#pragma unroll
    for (int o = 32; o > 0; o >>= 1) s += __shfl_xor(s, o);
    out[(size_t)row * 64 + lane] = v - m - logf(s);
}

extern "C" void kernel_launch(void* const* d_in, const int* in_sizes, int n_in,
                              void* d_out, int out_size, void* d_ws, size_t ws_size,
                              hipStream_t stream) {
    const float* x  = (const float*)d_in[0];
    const int*   ei = (const int*)d_in[1];
    const float* W1 = (const float*)d_in[2];
    const float* b1 = (const float*)d_in[3];
    const float* W2 = (const float*)d_in[4];
    const float* b2 = (const float*)d_in[5];

    const int N = in_sizes[0] / 128;   // 100000
    const int E = in_sizes[1] / 2;     // 1600000
    const int* src = ei;
    const int* dst = ei + E;

    // workspace layout (256B aligned)
    char* ws = (char*)d_ws;
    size_t off = 0;
    auto alloc = [&](size_t bytes) {
        void* p = ws + off;
        off += (bytes + 255) & ~(size_t)255;
        return p;
    };
    int*   cnt  = (int*)alloc((size_t)N * 4);
    float* dinv = (float*)alloc((size_t)N * 4);
    float* xw1  = (float*)alloc((size_t)N * 128 * 4);  // reused as hw2 after layer-1 scatter
    float* h1   = (float*)alloc((size_t)N * 128 * 4);
    float* hw2  = xw1;
    float* out  = (float*)d_out;

    hipMemsetAsync(cnt, 0, (size_t)N * 4, stream);
    k_deg<<<(E + THREADS - 1) / THREADS, THREADS, 0, stream>>>(dst, E, cnt);
    k_dinv<<<(N + THREADS - 1) / THREADS, THREADS, 0, stream>>>(cnt, N, dinv);

    // Layer 1
    k_gemm<128, false><<<(N + 63) / 64, THREADS, 0, stream>>>(x, W1, xw1, N);
    k_init<128><<<((size_t)N * 128 / 4 + THREADS - 1) / THREADS, THREADS, 0, stream>>>(
        xw1, dinv, b1, h1, N);
    k_scat128<<<4096, THREADS, 0, stream>>>(src, dst, E, dinv, xw1, h1);

    // Layer 2 (transform-then-aggregate: aggregate on 64-wide rows)
    k_gemm<64, true><<<(N + 63) / 64, THREADS, 0, stream>>>(h1, W2, hw2, N);
    k_init<64><<<((size_t)N * 64 / 4 + THREADS - 1) / THREADS, THREADS, 0, stream>>>(
        hw2, dinv, b2, out, N);
    k_scat64<<<4096, THREADS, 0, stream>>>(src, dst, E, dinv, hw2, out);

    k_lsm<<<(N + 3) / 4, THREADS, 0, stream>>>(out, N);
}

// Round 2
// 618.086 us; speedup vs baseline: 2.0768x; 2.0768x over previous
//
#include <hip/hip_runtime.h>
#include <cmath>

// GCN 2-layer forward on MI355X — round 2: CSR (dst-sorted) aggregation, no fp atomics.
// Pipeline: deg -> dinv -> scan(rowptr) -> fill(csr_src) ->
//           gemm1(x@W1) -> agg128 (bias+selfloop+edges, wave/node) ->
//           gemm2(relu(h1)@W2) -> agg64 -> log_softmax in-place.

#define THREADS 256

__global__ void k_deg(const int* __restrict__ dst, int E, int* __restrict__ cnt) {
    int i = blockIdx.x * blockDim.x + threadIdx.x;
    if (i < E) atomicAdd(&cnt[dst[i]], 1);
}

__global__ void k_dinv(const int* __restrict__ cnt, int N, float* __restrict__ dinv) {
    int i = blockIdx.x * blockDim.x + threadIdx.x;
    if (i < N) dinv[i] = rsqrtf((float)(cnt[i] + 1));  // +1 self-loop; always > 0
}

// ---- 3-phase exclusive scan of cnt[N] -> rowptr[N], 1024 items/block ----
__global__ void k_bsum(const int* __restrict__ cnt, int N, int* __restrict__ bsum) {
    __shared__ int sh[256];
    const int t = threadIdx.x;
    int base = blockIdx.x * 1024 + t * 4;
    int s = 0;
#pragma unroll
    for (int k = 0; k < 4; k++) { int i = base + k; if (i < N) s += cnt[i]; }
    sh[t] = s; __syncthreads();
    for (int o = 128; o > 0; o >>= 1) { if (t < o) sh[t] += sh[t + o]; __syncthreads(); }
    if (t == 0) bsum[blockIdx.x] = sh[0];
}

__global__ void k_bscan(const int* __restrict__ bsum, int NB, int* __restrict__ boff) {
    __shared__ int sh[128];  // NB <= 128
    const int t = threadIdx.x;
    int v = (t < NB) ? bsum[t] : 0;
    sh[t] = v; __syncthreads();
    for (int o = 1; o < 128; o <<= 1) {
        int add = (t >= o) ? sh[t - o] : 0;
        __syncthreads();
        sh[t] += add;
        __syncthreads();
    }
    if (t < NB) boff[t] = sh[t] - v;  // exclusive
}

__global__ void k_scan2(const int* __restrict__ cnt, int N, const int* __restrict__ boff,
                        int* __restrict__ rowptr) {
    __shared__ int sh[256];
    const int t = threadIdx.x;
    int base = blockIdx.x * 1024 + t * 4;
    int v[4]; int s = 0;
#pragma unroll
    for (int k = 0; k < 4; k++) { int i = base + k; v[k] = (i < N) ? cnt[i] : 0; s += v[k]; }
    sh[t] = s; __syncthreads();
    for (int o = 1; o < 256; o <<= 1) {
        int add = (t >= o) ? sh[t - o] : 0;
        __syncthreads();
        sh[t] += add;
        __syncthreads();
    }
    int excl = sh[t] - s + boff[blockIdx.x];
#pragma unroll
    for (int k = 0; k < 4; k++) {
        int i = base + k;
        if (i < N) { rowptr[i] = excl; excl += v[k]; }
    }
}

__global__ void k_fill(const int* __restrict__ src, const int* __restrict__ dst, int E,
                       const int* __restrict__ rowptr, int* __restrict__ fill,
                       int* __restrict__ csr_src) {
    int e = blockIdx.x * blockDim.x + threadIdx.x;
    if (e >= E) return;
    int d = dst[e];
    int pos = rowptr[d] + atomicAdd(&fill[d], 1);
    csr_src[pos] = src[e];
}

// C[M x NC] = A[M x 128] @ W[128 x NC], optional relu on A load.
template <int NC, bool RELU>
__global__ __launch_bounds__(256) void k_gemm(const float* __restrict__ A,
                                              const float* __restrict__ W,
                                              float* __restrict__ Out, int M) {
    constexpr int CG  = NC / 4;                // col groups (4 cols each)
    constexpr int RPT = (64 * NC) / (256 * 4); // rows per thread (128->8, 64->4)
    __shared__ float Wl[128 * NC];
    __shared__ float xs[64][8];
    const int tid = threadIdx.x;
    const int tx = tid % CG;
    const int ty = tid / CG;
    const int row0 = blockIdx.x * 64;

    for (int idx = tid * 4; idx < 128 * NC; idx += 256 * 4)
        *(float4*)&Wl[idx] = *(const float4*)&W[idx];

    float acc[RPT][4];
#pragma unroll
    for (int i = 0; i < RPT; i++)
#pragma unroll
        for (int j = 0; j < 4; j++) acc[i][j] = 0.f;

    const int lrow = tid >> 2;
    const int lk = (tid & 3) * 2;

    for (int k0 = 0; k0 < 128; k0 += 8) {
        __syncthreads();
        const int grow = row0 + lrow;
        float2 v = make_float2(0.f, 0.f);
        if (grow < M) v = *(const float2*)&A[(size_t)grow * 128 + k0 + lk];
        if (RELU) { v.x = fmaxf(v.x, 0.f); v.y = fmaxf(v.y, 0.f); }
        xs[lrow][lk] = v.x;
        xs[lrow][lk + 1] = v.y;
        __syncthreads();
#pragma unroll
        for (int kk = 0; kk < 8; kk++) {
            float4 wv = *(float4*)&Wl[(k0 + kk) * NC + tx * 4];
#pragma unroll
            for (int i = 0; i < RPT; i++) {
                float a = xs[ty * RPT + i][kk];
                acc[i][0] += a * wv.x;
                acc[i][1] += a * wv.y;
                acc[i][2] += a * wv.z;
                acc[i][3] += a * wv.w;
            }
        }
    }
#pragma unroll
    for (int i = 0; i < RPT; i++) {
        const int row = row0 + ty * RPT + i;
        if (row < M)
            *(float4*)&Out[(size_t)row * NC + tx * 4] =
                make_float4(acc[i][0], acc[i][1], acc[i][2], acc[i][3]);
    }
}

// One wave per destination node; lanes cover columns. Folds bias + self-loop.
template <int NC>
__global__ __launch_bounds__(256) void k_agg(const int* __restrict__ csr_src,
                                             const int* __restrict__ rowptr,
                                             const int* __restrict__ cnt,
                                             const float* __restrict__ dinv,
                                             const float* __restrict__ xw,
                                             const float* __restrict__ bias,
                                             float* __restrict__ out, int N) {
    const int lane = threadIdx.x & 63;
    const int i = (blockIdx.x * blockDim.x + threadIdx.x) >> 6;
    if (i >= N) return;
    const float di = dinv[i];
    const float* xrow = xw + (size_t)i * NC;
    float acc0 = di * di * xrow[lane];
    float acc1 = (NC == 128) ? di * di * xrow[64 + lane] : 0.f;
    const int start = rowptr[i];
    const int cn = cnt[i];
    int j = 0;
    for (; j + 2 <= cn; j += 2) {  // unroll-2 for memory-level parallelism
        int s0 = csr_src[start + j];
        int s1 = csr_src[start + j + 1];
        float w0 = dinv[s0] * di;
        float w1 = dinv[s1] * di;
        const float* r0 = xw + (size_t)s0 * NC;
        const float* r1 = xw + (size_t)s1 * NC;
        float a0 = r0[lane], b0 = (NC == 128) ? r0[64 + lane] : 0.f;
        float a1 = r1[lane], b1 = (NC == 128) ? r1[64 + lane] : 0.f;
        acc0 += w0 * a0; acc1 += w0 * b0;
        acc0 += w1 * a1; acc1 += w1 * b1;
    }
    if (j < cn) {
        int s0 = csr_src[start + j];
        float w0 = dinv[s0] * di;
        const float* r0 = xw + (size_t)s0 * NC;
        acc0 += w0 * r0[lane];
        if (NC == 128) acc1 += w0 * r0[64 + lane];
    }
    out[(size_t)i * NC + lane] = bias[lane] + acc0;
    if (NC == 128) out[(size_t)i * NC + 64 + lane] = bias[64 + lane] + acc1;
}

// In-place log_softmax over 64 cols; one wave per row.
__global__ void k_lsm(float* __restrict__ out, int N) {
    const int lane = threadIdx.x & 63;
    const int row = (blockIdx.x * blockDim.x + threadIdx.x) >> 6;
    if (row >= N) return;
    float v = out[(size_t)row * 64 + lane];
    float m = v;
#pragma unroll
    for (int o = 32; o > 0; o >>= 1) m = fmaxf(m, __shfl_xor(m, o));
    float e = expf(v - m);
    float s = e;
#pragma unroll
    for (int o = 32; o > 0; o >>= 1) s += __shfl_xor(s, o);
    out[(size_t)row * 64 + lane] = v - m - logf(s);
}

extern "C" void kernel_launch(void* const* d_in, const int* in_sizes, int n_in,
                              void* d_out, int out_size, void* d_ws, size_t ws_size,
                              hipStream_t stream) {
    const float* x  = (const float*)d_in[0];
    const int*   ei = (const int*)d_in[1];
    const float* W1 = (const float*)d_in[2];
    const float* b1 = (const float*)d_in[3];
    const float* W2 = (const float*)d_in[4];
    const float* b2 = (const float*)d_in[5];

    const int N = in_sizes[0] / 128;   // 100000
    const int E = in_sizes[1] / 2;     // 1600000
    const int* src = ei;
    const int* dst = ei + E;
    const int NB = (N + 1023) / 1024;  // scan blocks (<=128)

    // workspace layout (256B aligned)
    char* ws = (char*)d_ws;
    size_t off = 0;
    auto alloc = [&](size_t bytes) {
        void* p = ws + off;
        off += (bytes + 255) & ~(size_t)255;
        return p;
    };
    int*   cnt     = (int*)alloc((size_t)N * 4);
    float* dinv    = (float*)alloc((size_t)N * 4);
    int*   rowptr  = (int*)alloc((size_t)N * 4);
    int*   csr_src = (int*)alloc((size_t)E * 4);
    float* xw1     = (float*)alloc((size_t)N * 128 * 4);  // reused as hw2 after layer-1 agg
    float* h1      = (float*)alloc((size_t)N * 128 * 4);
    float* hw2     = xw1;
    float* out     = (float*)d_out;

    // transient scan/fill arrays live in d_out (scratch until final agg writes it)
    int* fill = (int*)d_out;                 // N ints
    int* bsum = fill + N;                    // NB ints
    int* boff = bsum + 256;                  // NB ints   (fits: 100k+512 ints << 6.4M floats)

    hipMemsetAsync(cnt, 0, (size_t)N * 4, stream);
    hipMemsetAsync(fill, 0, (size_t)N * 4, stream);

    k_deg<<<(E + THREADS - 1) / THREADS, THREADS, 0, stream>>>(dst, E, cnt);
    k_dinv<<<(N + THREADS - 1) / THREADS, THREADS, 0, stream>>>(cnt, N, dinv);
    k_bsum<<<NB, THREADS, 0, stream>>>(cnt, N, bsum);
    k_bscan<<<1, 128, 0, stream>>>(bsum, NB, boff);
    k_scan2<<<NB, THREADS, 0, stream>>>(cnt, N, boff, rowptr);
    k_fill<<<(E + THREADS - 1) / THREADS, THREADS, 0, stream>>>(src, dst, E, rowptr, fill, csr_src);

    // Layer 1
    k_gemm<128, false><<<(N + 63) / 64, THREADS, 0, stream>>>(x, W1, xw1, N);
    k_agg<128><<<(N * 64 + THREADS - 1) / THREADS, THREADS, 0, stream>>>(
        csr_src, rowptr, cnt, dinv, xw1, b1, h1, N);

    // Layer 2 (transform-then-aggregate: aggregate on 64-wide rows)
    k_gemm<64, true><<<(N + 63) / 64, THREADS, 0, stream>>>(h1, W2, hw2, N);
    k_agg<64><<<(N * 64 + THREADS - 1) / THREADS, THREADS, 0, stream>>>(
        csr_src, rowptr, cnt, dinv, hw2, b2, out, N);

    k_lsm<<<(N * 64 + THREADS - 1) / THREADS, THREADS, 0, stream>>>(out, N);
}

// Round 3
// 461.355 us; speedup vs baseline: 2.7823x; 1.3397x over previous
//
#include <hip/hip_runtime.h>
#include <cmath>

// GCN 2-layer forward on MI355X — round 3: bf16 MFMA GEMMs + bf16 gather domain.
// Pipeline: deg -> dinv -> scan(rowptr) -> fill(csr_src) -> castW ->
//           gemm1_mfma(x@W1 -> bf16) -> agg128 (bias+selfloop+relu -> bf16 h1) ->
//           gemm2_mfma(h1@W2 -> bf16) -> agg64 (bias+selfloop -> fp32 out) -> log_softmax.

#define THREADS 256

__device__ __forceinline__ unsigned short f2bf(float f) {
    union { float f; unsigned u; } v; v.f = f;
    unsigned r = v.u + 0x7FFFu + ((v.u >> 16) & 1u);   // round-nearest-even
    return (unsigned short)(r >> 16);
}
__device__ __forceinline__ float bf_lo(unsigned u) {
    union { unsigned u; float f; } v; v.u = u << 16; return v.f;
}
__device__ __forceinline__ float bf_hi(unsigned u) {
    union { unsigned u; float f; } v; v.u = u & 0xFFFF0000u; return v.f;
}

__global__ void k_deg(const int* __restrict__ dst, int E, int* __restrict__ cnt) {
    int i = blockIdx.x * blockDim.x + threadIdx.x;
    if (i < E) atomicAdd(&cnt[dst[i]], 1);
}

__global__ void k_dinv(const int* __restrict__ cnt, int N, float* __restrict__ dinv) {
    int i = blockIdx.x * blockDim.x + threadIdx.x;
    if (i < N) dinv[i] = rsqrtf((float)(cnt[i] + 1));  // +1 self-loop
}

// ---- 3-phase exclusive scan of cnt[N] -> rowptr[N], 1024 items/block ----
__global__ void k_bsum(const int* __restrict__ cnt, int N, int* __restrict__ bsum) {
    __shared__ int sh[256];
    const int t = threadIdx.x;
    int base = blockIdx.x * 1024 + t * 4;
    int s = 0;
#pragma unroll
    for (int k = 0; k < 4; k++) { int i = base + k; if (i < N) s += cnt[i]; }
    sh[t] = s; __syncthreads();
    for (int o = 128; o > 0; o >>= 1) { if (t < o) sh[t] += sh[t + o]; __syncthreads(); }
    if (t == 0) bsum[blockIdx.x] = sh[0];
}

__global__ void k_bscan(const int* __restrict__ bsum, int NB, int* __restrict__ boff) {
    __shared__ int sh[128];  // NB <= 128
    const int t = threadIdx.x;
    int v = (t < NB) ? bsum[t] : 0;
    sh[t] = v; __syncthreads();
    for (int o = 1; o < 128; o <<= 1) {
        int add = (t >= o) ? sh[t - o] : 0;
        __syncthreads();
        sh[t] += add;
        __syncthreads();
    }
    if (t < NB) boff[t] = sh[t] - v;  // exclusive
}

__global__ void k_scan2(const int* __restrict__ cnt, int N, const int* __restrict__ boff,
                        int* __restrict__ rowptr) {
    __shared__ int sh[256];
    const int t = threadIdx.x;
    int base = blockIdx.x * 1024 + t * 4;
    int v[4]; int s = 0;
#pragma unroll
    for (int k = 0; k < 4; k++) { int i = base + k; v[k] = (i < N) ? cnt[i] : 0; s += v[k]; }
    sh[t] = s; __syncthreads();
    for (int o = 1; o < 256; o <<= 1) {
        int add = (t >= o) ? sh[t - o] : 0;
        __syncthreads();
        sh[t] += add;
        __syncthreads();
    }
    int excl = sh[t] - s + boff[blockIdx.x];
#pragma unroll
    for (int k = 0; k < 4; k++) {
        int i = base + k;
        if (i < N) { rowptr[i] = excl; excl += v[k]; }
    }
}

__global__ void k_fill(const int* __restrict__ src, const int* __restrict__ dst, int E,
                       const int* __restrict__ rowptr, int* __restrict__ fill,
                       int* __restrict__ csr_src) {
    int e = blockIdx.x * blockDim.x + threadIdx.x;
    if (e >= E) return;
    int d = dst[e];
    int pos = rowptr[d] + atomicAdd(&fill[d], 1);
    csr_src[pos] = src[e];
}

// Wt1[n][k] = bf16(W1[k][n]) (128x128), Wt2[n][k] = bf16(W2[k][n]) (64x128)
__global__ void k_castW(const float* __restrict__ W1, const float* __restrict__ W2,
                        unsigned short* __restrict__ Wt1, unsigned short* __restrict__ Wt2) {
    int idx = blockIdx.x * blockDim.x + threadIdx.x;
    if (idx < 16384) {
        int n = idx >> 7, k = idx & 127;
        Wt1[idx] = f2bf(W1[k * 128 + n]);
    } else if (idx < 16384 + 8192) {
        int t = idx - 16384;
        int n = t >> 7, k = t & 127;
        Wt2[t] = f2bf(W2[k * 64 + n]);
    }
}

// C[M x NC](bf16) = A[M x 128] @ Wt^T, Wt is [NC x 128] bf16 (pre-transposed W).
// Block 256 = 4 waves; 64 rows/block; wave w -> rows [16w,16w+16) x all NC cols.
// mfma_f32_16x16x32_bf16: A-frag lane l = A[m=l&15][k=(l>>4)*8+j]; C/D row=(l>>4)*4+r, col=l&15.
typedef __attribute__((ext_vector_type(8))) short bf16x8;
typedef __attribute__((ext_vector_type(4))) float f32x4;

template <int NC, bool A_BF16>
__global__ __launch_bounds__(256) void k_gemm_mfma(const void* __restrict__ Av,
                                                   const unsigned short* __restrict__ Wt,
                                                   unsigned short* __restrict__ Out, int M) {
    constexpr int KP = 136;                 // padded k-stride (272 B: 4-bank row shift, 16B-aligned)
    __shared__ __align__(16) short As[64 * KP];
    __shared__ __align__(16) short Bs[NC * KP];
    const int tid = threadIdx.x;
    const int row0 = blockIdx.x * 64;

    if (A_BF16) {
        const unsigned short* A = (const unsigned short*)Av;
#pragma unroll
        for (int q = 0; q < 4; q++) {
            int f = tid + 256 * q;          // 0..1023, 16 x ushort8 per row
            int r = f >> 4, c = (f & 15) * 8;
            uint4 v = make_uint4(0, 0, 0, 0);
            if (row0 + r < M) v = *(const uint4*)&A[(size_t)(row0 + r) * 128 + c];
            *(uint4*)&As[r * KP + c] = v;
        }
    } else {
        const float* A = (const float*)Av;
#pragma unroll
        for (int q = 0; q < 8; q++) {
            int f = tid + 256 * q;          // 0..2047, 32 x float4 per row
            int r = f >> 5, c = (f & 31) * 4;
            float4 v = make_float4(0.f, 0.f, 0.f, 0.f);
            if (row0 + r < M) v = *(const float4*)&A[(size_t)(row0 + r) * 128 + c];
            ushort4 o;
            o.x = f2bf(v.x); o.y = f2bf(v.y); o.z = f2bf(v.z); o.w = f2bf(v.w);
            *(ushort4*)&As[r * KP + c] = o;
        }
    }
    for (int f = tid; f < NC * 16; f += 256) {     // Wt: NC x 128 bf16, ushort8 chunks
        int n = f >> 4, c = (f & 15) * 8;
        *(uint4*)&Bs[n * KP + c] = *(const uint4*)&Wt[n * 128 + c];
    }
    __syncthreads();

    const int wave = tid >> 6, lane = tid & 63;
    const int m = lane & 15, quad = lane >> 4;
    constexpr int CT = NC / 16;
    f32x4 acc[CT] = {};
    const short* arow = &As[(16 * wave + m) * KP + quad * 8];
    const short* brow = &Bs[m * KP + quad * 8];
#pragma unroll
    for (int k0 = 0; k0 < 128; k0 += 32) {
        bf16x8 a = *(const bf16x8*)&arow[k0];
#pragma unroll
        for (int c = 0; c < CT; c++) {
            bf16x8 b = *(const bf16x8*)&brow[(size_t)c * 16 * KP + k0];
            acc[c] = __builtin_amdgcn_mfma_f32_16x16x32_bf16(a, b, acc[c], 0, 0, 0);
        }
    }

    // repack through LDS for coalesced bf16 stores
    __syncthreads();
    short* Cs = As;                         // reuse (64*NC <= 64*KP)
#pragma unroll
    for (int c = 0; c < CT; c++)
#pragma unroll
        for (int r = 0; r < 4; r++)
            Cs[(16 * wave + quad * 4 + r) * NC + 16 * c + m] = (short)f2bf(acc[c][r]);
    __syncthreads();
    for (int f = tid; f < 64 * NC / 8; f += 256) {
        int r = f / (NC / 8), c = (f % (NC / 8)) * 8;
        if (row0 + r < M)
            *(uint4*)&Out[(size_t)(row0 + r) * NC + c] = *(const uint4*)&Cs[r * NC + c];
    }
}

// Aggregate 128-wide bf16 rows. One wave per node; lane covers cols {2l, 2l+1} (one uint).
// Folds bias + self-loop + ReLU; writes bf16.
__global__ __launch_bounds__(256) void k_agg128b(const int* __restrict__ csr_src,
                                                 const int* __restrict__ rowptr,
                                                 const int* __restrict__ cnt,
                                                 const float* __restrict__ dinv,
                                                 const unsigned* __restrict__ xw,
                                                 const float* __restrict__ bias,
                                                 unsigned* __restrict__ h1, int N) {
    const int lane = threadIdx.x & 63;
    const int i = (blockIdx.x * blockDim.x + threadIdx.x) >> 6;
    if (i >= N) return;
    const float di = dinv[i];
    unsigned u = xw[(size_t)i * 64 + lane];
    float acc0 = di * di * bf_lo(u);
    float acc1 = di * di * bf_hi(u);
    const int start = rowptr[i], cn = cnt[i];
    int j = 0;
    for (; j + 4 <= cn; j += 4) {
        int s0 = csr_src[start + j];
        int s1 = csr_src[start + j + 1];
        int s2 = csr_src[start + j + 2];
        int s3 = csr_src[start + j + 3];
        float w0 = dinv[s0] * di, w1 = dinv[s1] * di;
        float w2 = dinv[s2] * di, w3 = dinv[s3] * di;
        unsigned u0 = xw[(size_t)s0 * 64 + lane];
        unsigned u1 = xw[(size_t)s1 * 64 + lane];
        unsigned u2 = xw[(size_t)s2 * 64 + lane];
        unsigned u3 = xw[(size_t)s3 * 64 + lane];
        acc0 += w0 * bf_lo(u0); acc1 += w0 * bf_hi(u0);
        acc0 += w1 * bf_lo(u1); acc1 += w1 * bf_hi(u1);
        acc0 += w2 * bf_lo(u2); acc1 += w2 * bf_hi(u2);
        acc0 += w3 * bf_lo(u3); acc1 += w3 * bf_hi(u3);
    }
    for (; j < cn; j++) {
        int s0 = csr_src[start + j];
        float w0 = dinv[s0] * di;
        unsigned u0 = xw[(size_t)s0 * 64 + lane];
        acc0 += w0 * bf_lo(u0); acc1 += w0 * bf_hi(u0);
    }
    float2 b = *(const float2*)&bias[2 * lane];
    float r0 = fmaxf(acc0 + b.x, 0.f);   // ReLU folded (layer-1 epilogue)
    float r1 = fmaxf(acc1 + b.y, 0.f);
    h1[(size_t)i * 64 + lane] = (unsigned)f2bf(r0) | ((unsigned)f2bf(r1) << 16);
}

// Aggregate 64-wide bf16 rows. One wave per node, half-wave per edge (2 edges in flight).
// Writes fp32 (bias + self-loop folded).
__global__ __launch_bounds__(256) void k_agg64b(const int* __restrict__ csr_src,
                                                const int* __restrict__ rowptr,
                                                const int* __restrict__ cnt,
                                                const float* __restrict__ dinv,
                                                const unsigned* __restrict__ xw,
                                                const float* __restrict__ bias,
                                                float* __restrict__ out, int N) {
    const int lane = threadIdx.x & 63;
    const int i = (blockIdx.x * blockDim.x + threadIdx.x) >> 6;
    if (i >= N) return;
    const int h = lane >> 5, sl = lane & 31;
    const float di = dinv[i];
    float acc0 = 0.f, acc1 = 0.f;
    if (h == 0) {
        unsigned u = xw[(size_t)i * 32 + sl];
        acc0 = di * di * bf_lo(u);
        acc1 = di * di * bf_hi(u);
    }
    const int start = rowptr[i], cn = cnt[i];
    int e = h;
    for (; e + 2 < cn; e += 4) {       // each half: edges e, e+2
        int s0 = csr_src[start + e];
        int s1 = csr_src[start + e + 2];
        float w0 = dinv[s0] * di, w1 = dinv[s1] * di;
        unsigned u0 = xw[(size_t)s0 * 32 + sl];
        unsigned u1 = xw[(size_t)s1 * 32 + sl];
        acc0 += w0 * bf_lo(u0); acc1 += w0 * bf_hi(u0);
        acc0 += w1 * bf_lo(u1); acc1 += w1 * bf_hi(u1);
    }
    for (; e < cn; e += 2) {
        int s0 = csr_src[start + e];
        float w0 = dinv[s0] * di;
        unsigned u0 = xw[(size_t)s0 * 32 + sl];
        acc0 += w0 * bf_lo(u0); acc1 += w0 * bf_hi(u0);
    }
    acc0 += __shfl_xor(acc0, 32);
    acc1 += __shfl_xor(acc1, 32);
    if (h == 0) {
        float2 b = *(const float2*)&bias[2 * sl];
        *(float2*)&out[(size_t)i * 64 + 2 * sl] = make_float2(acc0 + b.x, acc1 + b.y);
    }
}

// In-place log_softmax over 64 cols; one wave per row.
__global__ void k_lsm(float* __restrict__ out, int N) {
    const int lane = threadIdx.x & 63;
    const int row = (blockIdx.x * blockDim.x + threadIdx.x) >> 6;
    if (row >= N) return;
    float v = out[(size_t)row * 64 + lane];
    float m = v;
#pragma unroll
    for (int o = 32; o > 0; o >>= 1) m = fmaxf(m, __shfl_xor(m, o));
    float e = expf(v - m);
    float s = e;
#pragma unroll
    for (int o = 32; o > 0; o >>= 1) s += __shfl_xor(s, o);
    out[(size_t)row * 64 + lane] = v - m - logf(s);
}

extern "C" void kernel_launch(void* const* d_in, const int* in_sizes, int n_in,
                              void* d_out, int out_size, void* d_ws, size_t ws_size,
                              hipStream_t stream) {
    const float* x  = (const float*)d_in[0];
    const int*   ei = (const int*)d_in[1];
    const float* W1 = (const float*)d_in[2];
    const float* b1 = (const float*)d_in[3];
    const float* W2 = (const float*)d_in[4];
    const float* b2 = (const float*)d_in[5];

    const int N = in_sizes[0] / 128;   // 100000
    const int E = in_sizes[1] / 2;     // 1600000
    const int* src = ei;
    const int* dst = ei + E;
    const int NB = (N + 1023) / 1024;  // scan blocks (<=128)

    char* ws = (char*)d_ws;
    size_t off = 0;
    auto alloc = [&](size_t bytes) {
        void* p = ws + off;
        off += (bytes + 255) & ~(size_t)255;
        return p;
    };
    int*            cnt     = (int*)alloc((size_t)N * 4);
    float*          dinv    = (float*)alloc((size_t)N * 4);
    int*            rowptr  = (int*)alloc((size_t)N * 4);
    int*            csr_src = (int*)alloc((size_t)E * 4);
    unsigned short* Wt1     = (unsigned short*)alloc(128 * 128 * 2);
    unsigned short* Wt2     = (unsigned short*)alloc(64 * 128 * 2);
    unsigned short* xw1     = (unsigned short*)alloc((size_t)N * 128 * 2);  // bf16; reused as hw2
    unsigned short* h1      = (unsigned short*)alloc((size_t)N * 128 * 2);  // bf16
    unsigned short* hw2     = xw1;
    float*          out     = (float*)d_out;

    // transient fill array lives in d_out (scratch until final agg writes it)
    int* fill = (int*)d_out;
    int* bsum = fill + N;
    int* boff = bsum + 256;

    hipMemsetAsync(cnt, 0, (size_t)N * 4, stream);
    hipMemsetAsync(fill, 0, (size_t)N * 4, stream);

    k_deg<<<(E + THREADS - 1) / THREADS, THREADS, 0, stream>>>(dst, E, cnt);
    k_dinv<<<(N + THREADS - 1) / THREADS, THREADS, 0, stream>>>(cnt, N, dinv);
    k_bsum<<<NB, THREADS, 0, stream>>>(cnt, N, bsum);
    k_bscan<<<1, 128, 0, stream>>>(bsum, NB, boff);
    k_scan2<<<NB, THREADS, 0, stream>>>(cnt, N, boff, rowptr);
    k_fill<<<(E + THREADS - 1) / THREADS, THREADS, 0, stream>>>(src, dst, E, rowptr, fill, csr_src);
    k_castW<<<96, THREADS, 0, stream>>>(W1, W2, Wt1, Wt2);

    // Layer 1
    k_gemm_mfma<128, false><<<(N + 63) / 64, THREADS, 0, stream>>>(x, Wt1, xw1, N);
    k_agg128b<<<(N * 64 + THREADS - 1) / THREADS, THREADS, 0, stream>>>(
        csr_src, rowptr, cnt, dinv, (const unsigned*)xw1, b1, (unsigned*)h1, N);

    // Layer 2
    k_gemm_mfma<64, true><<<(N + 63) / 64, THREADS, 0, stream>>>(h1, Wt2, hw2, N);
    k_agg64b<<<(N * 64 + THREADS - 1) / THREADS, THREADS, 0, stream>>>(
        csr_src, rowptr, cnt, dinv, (const unsigned*)hw2, b2, out, N);

    k_lsm<<<(N * 64 + THREADS - 1) / THREADS, THREADS, 0, stream>>>(out, N);
}

// Round 4
// 348.389 us; speedup vs baseline: 3.6845x; 1.3243x over previous
//
#include <hip/hip_runtime.h>
#include <cmath>

// GCN 2-layer forward on MI355X — round 4: bucketed XCD-local CSR build.
// Pipeline: bcount -> bscan -> bscatter(pairs) -> bbuild(deg/dinv/rowptr/csr_src) ->
//           gemm1_mfma(x@W1 -> bf16) -> agg128 (bias+selfloop+relu -> bf16 h1) ->
//           gemm2_mfma(h1@W2 -> bf16) -> agg64 (bias+selfloop -> fp32 out) -> log_softmax.

#define THREADS 256
#define BSHIFT 8                      // 256 nodes per bucket
#define MAXB 512                      // >= ceil(N / 256)

__device__ __forceinline__ unsigned short f2bf(float f) {
    union { float f; unsigned u; } v; v.f = f;
    unsigned r = v.u + 0x7FFFu + ((v.u >> 16) & 1u);   // round-nearest-even
    return (unsigned short)(r >> 16);
}
__device__ __forceinline__ float bf_lo(unsigned u) {
    union { unsigned u; float f; } v; v.u = u << 16; return v.f;
}
__device__ __forceinline__ float bf_hi(unsigned u) {
    union { unsigned u; float f; } v; v.u = u & 0xFFFF0000u; return v.f;
}

// ---- bucket count: LDS histogram, flush once per block ----
__global__ __launch_bounds__(256) void k_bcount(const int* __restrict__ dst, int E, int B,
                                                int* __restrict__ bcnt) {
    __shared__ int lc[MAXB];
    for (int i = threadIdx.x; i < MAXB; i += 256) lc[i] = 0;
    __syncthreads();
    for (int e = blockIdx.x * blockDim.x + threadIdx.x; e < E; e += gridDim.x * blockDim.x)
        atomicAdd(&lc[dst[e] >> BSHIFT], 1);
    __syncthreads();
    for (int b = threadIdx.x; b < B; b += 256)
        if (lc[b]) atomicAdd(&bcnt[b], lc[b]);
}

// ---- exclusive scan of bcnt[B] -> boff[B+1], single block of 512 ----
__global__ void k_bscan(const int* __restrict__ bcnt, int B, int* __restrict__ boff) {
    __shared__ int sh[MAXB];
    const int t = threadIdx.x;
    int v = (t < B) ? bcnt[t] : 0;
    sh[t] = v; __syncthreads();
    for (int o = 1; o < MAXB; o <<= 1) {
        int add = (t >= o) ? sh[t - o] : 0;
        __syncthreads();
        sh[t] += add;
        __syncthreads();
    }
    if (t < B) boff[t] = sh[t] - v;
    if (t == B - 1) boff[B] = sh[t];
}

// ---- scatter edges into bucket-contiguous (src,dst) pairs, block-staged ----
__global__ __launch_bounds__(256) void k_bscatter(const int* __restrict__ src,
                                                  const int* __restrict__ dst, int E, int B,
                                                  const int* __restrict__ boff,
                                                  int* __restrict__ bfill,
                                                  uint2* __restrict__ pairs) {
    __shared__ int lc[MAXB];     // per-block bucket count, then per-bucket rank
    __shared__ int lbase[MAXB];  // global reservation base within bucket
    const int tid = threadIdx.x;
    const int e0 = blockIdx.x * 8192;
    for (int i = tid; i < MAXB; i += 256) lc[i] = 0;
    __syncthreads();
#pragma unroll
    for (int k = 0; k < 32; k++) {
        int e = e0 + k * 256 + tid;
        if (e < E) atomicAdd(&lc[dst[e] >> BSHIFT], 1);
    }
    __syncthreads();
    for (int b = tid; b < B; b += 256)
        lbase[b] = lc[b] ? atomicAdd(&bfill[b], lc[b]) : 0;
    __syncthreads();
    for (int i = tid; i < MAXB; i += 256) lc[i] = 0;  // reuse as rank
    __syncthreads();
#pragma unroll
    for (int k = 0; k < 32; k++) {
        int e = e0 + k * 256 + tid;
        if (e < E) {
            int s = src[e], d = dst[e];
            int b = d >> BSHIFT;
            int r = atomicAdd(&lc[b], 1);
            pairs[(size_t)boff[b] + lbase[b] + r] = make_uint2((unsigned)s, (unsigned)d);
        }
    }
}

// ---- per-bucket CSR build: one block per bucket; all scatter is XCD-local ----
__global__ __launch_bounds__(256) void k_bbuild(const uint2* __restrict__ pairs,
                                                const int* __restrict__ boff, int N,
                                                int* __restrict__ deg,
                                                float* __restrict__ dinv,
                                                int* __restrict__ rowptr,
                                                int* __restrict__ csr_src) {
    __shared__ int ldeg[256], lex[256], lrank[256];
    const int b = blockIdx.x, tid = threadIdx.x;
    const int node0 = b << BSHIFT;
    const int base = boff[b];
    const int cnt_e = boff[b + 1] - base;
    ldeg[tid] = 0;
    __syncthreads();
    for (int e = tid; e < cnt_e; e += 256)
        atomicAdd(&ldeg[(int)pairs[base + e].y - node0], 1);
    __syncthreads();
    int v = ldeg[tid];
    lex[tid] = v; __syncthreads();
    for (int o = 1; o < 256; o <<= 1) {
        int add = (tid >= o) ? lex[tid - o] : 0;
        __syncthreads();
        lex[tid] += add;
        __syncthreads();
    }
    int excl = lex[tid] - v;
    if (node0 + tid < N) {
        deg[node0 + tid] = v;
        dinv[node0 + tid] = rsqrtf((float)(v + 1));
        rowptr[node0 + tid] = base + excl;
    }
    __syncthreads();
    lex[tid] = excl;       // keep exclusive offsets
    lrank[tid] = 0;
    __syncthreads();
    for (int e = tid; e < cnt_e; e += 256) {
        uint2 p = pairs[base + e];
        int loc = (int)p.y - node0;
        int r = atomicAdd(&lrank[loc], 1);
        csr_src[base + lex[loc] + r] = (int)p.x;
    }
}

// Wt1[n][k] = bf16(W1[k][n]) (128x128), Wt2[n][k] = bf16(W2[k][n]) (64x128)
__global__ void k_castW(const float* __restrict__ W1, const float* __restrict__ W2,
                        unsigned short* __restrict__ Wt1, unsigned short* __restrict__ Wt2) {
    int idx = blockIdx.x * blockDim.x + threadIdx.x;
    if (idx < 16384) {
        int n = idx >> 7, k = idx & 127;
        Wt1[idx] = f2bf(W1[k * 128 + n]);
    } else if (idx < 16384 + 8192) {
        int t = idx - 16384;
        int n = t >> 7, k = t & 127;
        Wt2[t] = f2bf(W2[k * 64 + n]);
    }
}

// C[M x NC](bf16) = A[M x 128] @ Wt^T, Wt is [NC x 128] bf16 (pre-transposed W).
typedef __attribute__((ext_vector_type(8))) short bf16x8;
typedef __attribute__((ext_vector_type(4))) float f32x4;

template <int NC, bool A_BF16>
__global__ __launch_bounds__(256) void k_gemm_mfma(const void* __restrict__ Av,
                                                   const unsigned short* __restrict__ Wt,
                                                   unsigned short* __restrict__ Out, int M) {
    constexpr int KP = 136;                 // padded k-stride
    __shared__ __align__(16) short As[64 * KP];
    __shared__ __align__(16) short Bs[NC * KP];
    const int tid = threadIdx.x;
    const int row0 = blockIdx.x * 64;

    if (A_BF16) {
        const unsigned short* A = (const unsigned short*)Av;
#pragma unroll
        for (int q = 0; q < 4; q++) {
            int f = tid + 256 * q;
            int r = f >> 4, c = (f & 15) * 8;
            uint4 v = make_uint4(0, 0, 0, 0);
            if (row0 + r < M) v = *(const uint4*)&A[(size_t)(row0 + r) * 128 + c];
            *(uint4*)&As[r * KP + c] = v;
        }
    } else {
        const float* A = (const float*)Av;
#pragma unroll
        for (int q = 0; q < 8; q++) {
            int f = tid + 256 * q;
            int r = f >> 5, c = (f & 31) * 4;
            float4 v = make_float4(0.f, 0.f, 0.f, 0.f);
            if (row0 + r < M) v = *(const float4*)&A[(size_t)(row0 + r) * 128 + c];
            ushort4 o;
            o.x = f2bf(v.x); o.y = f2bf(v.y); o.z = f2bf(v.z); o.w = f2bf(v.w);
            *(ushort4*)&As[r * KP + c] = o;
        }
    }
    for (int f = tid; f < NC * 16; f += 256) {
        int n = f >> 4, c = (f & 15) * 8;
        *(uint4*)&Bs[n * KP + c] = *(const uint4*)&Wt[n * 128 + c];
    }
    __syncthreads();

    const int wave = tid >> 6, lane = tid & 63;
    const int m = lane & 15, quad = lane >> 4;
    constexpr int CT = NC / 16;
    f32x4 acc[CT] = {};
    const short* arow = &As[(16 * wave + m) * KP + quad * 8];
    const short* brow = &Bs[m * KP + quad * 8];
#pragma unroll
    for (int k0 = 0; k0 < 128; k0 += 32) {
        bf16x8 a = *(const bf16x8*)&arow[k0];
#pragma unroll
        for (int c = 0; c < CT; c++) {
            bf16x8 b = *(const bf16x8*)&brow[(size_t)c * 16 * KP + k0];
            acc[c] = __builtin_amdgcn_mfma_f32_16x16x32_bf16(a, b, acc[c], 0, 0, 0);
        }
    }

    __syncthreads();
    short* Cs = As;
#pragma unroll
    for (int c = 0; c < CT; c++)
#pragma unroll
        for (int r = 0; r < 4; r++)
            Cs[(16 * wave + quad * 4 + r) * NC + 16 * c + m] = (short)f2bf(acc[c][r]);
    __syncthreads();
    for (int f = tid; f < 64 * NC / 8; f += 256) {
        int r = f / (NC / 8), c = (f % (NC / 8)) * 8;
        if (row0 + r < M)
            *(uint4*)&Out[(size_t)(row0 + r) * NC + c] = *(const uint4*)&Cs[r * NC + c];
    }
}

// Aggregate 128-wide bf16 rows. One wave per node; lane covers cols {2l, 2l+1}.
__global__ __launch_bounds__(256) void k_agg128b(const int* __restrict__ csr_src,
                                                 const int* __restrict__ rowptr,
                                                 const int* __restrict__ cnt,
                                                 const float* __restrict__ dinv,
                                                 const unsigned* __restrict__ xw,
                                                 const float* __restrict__ bias,
                                                 unsigned* __restrict__ h1, int N) {
    const int lane = threadIdx.x & 63;
    const int i = (blockIdx.x * blockDim.x + threadIdx.x) >> 6;
    if (i >= N) return;
    const float di = dinv[i];
    unsigned u = xw[(size_t)i * 64 + lane];
    float acc0 = di * di * bf_lo(u);
    float acc1 = di * di * bf_hi(u);
    const int start = rowptr[i], cn = cnt[i];
    int j = 0;
    for (; j + 4 <= cn; j += 4) {
        int s0 = csr_src[start + j];
        int s1 = csr_src[start + j + 1];
        int s2 = csr_src[start + j + 2];
        int s3 = csr_src[start + j + 3];
        float w0 = dinv[s0] * di, w1 = dinv[s1] * di;
        float w2 = dinv[s2] * di, w3 = dinv[s3] * di;
        unsigned u0 = xw[(size_t)s0 * 64 + lane];
        unsigned u1 = xw[(size_t)s1 * 64 + lane];
        unsigned u2 = xw[(size_t)s2 * 64 + lane];
        unsigned u3 = xw[(size_t)s3 * 64 + lane];
        acc0 += w0 * bf_lo(u0); acc1 += w0 * bf_hi(u0);
        acc0 += w1 * bf_lo(u1); acc1 += w1 * bf_hi(u1);
        acc0 += w2 * bf_lo(u2); acc1 += w2 * bf_hi(u2);
        acc0 += w3 * bf_lo(u3); acc1 += w3 * bf_hi(u3);
    }
    for (; j < cn; j++) {
        int s0 = csr_src[start + j];
        float w0 = dinv[s0] * di;
        unsigned u0 = xw[(size_t)s0 * 64 + lane];
        acc0 += w0 * bf_lo(u0); acc1 += w0 * bf_hi(u0);
    }
    float2 b = *(const float2*)&bias[2 * lane];
    float r0 = fmaxf(acc0 + b.x, 0.f);
    float r1 = fmaxf(acc1 + b.y, 0.f);
    h1[(size_t)i * 64 + lane] = (unsigned)f2bf(r0) | ((unsigned)f2bf(r1) << 16);
}

// Aggregate 64-wide bf16 rows. One wave per node, half-wave per edge.
__global__ __launch_bounds__(256) void k_agg64b(const int* __restrict__ csr_src,
                                                const int* __restrict__ rowptr,
                                                const int* __restrict__ cnt,
                                                const float* __restrict__ dinv,
                                                const unsigned* __restrict__ xw,
                                                const float* __restrict__ bias,
                                                float* __restrict__ out, int N) {
    const int lane = threadIdx.x & 63;
    const int i = (blockIdx.x * blockDim.x + threadIdx.x) >> 6;
    if (i >= N) return;
    const int h = lane >> 5, sl = lane & 31;
    const float di = dinv[i];
    float acc0 = 0.f, acc1 = 0.f;
    if (h == 0) {
        unsigned u = xw[(size_t)i * 32 + sl];
        acc0 = di * di * bf_lo(u);
        acc1 = di * di * bf_hi(u);
    }
    const int start = rowptr[i], cn = cnt[i];
    int e = h;
    for (; e + 2 < cn; e += 4) {
        int s0 = csr_src[start + e];
        int s1 = csr_src[start + e + 2];
        float w0 = dinv[s0] * di, w1 = dinv[s1] * di;
        unsigned u0 = xw[(size_t)s0 * 32 + sl];
        unsigned u1 = xw[(size_t)s1 * 32 + sl];
        acc0 += w0 * bf_lo(u0); acc1 += w0 * bf_hi(u0);
        acc0 += w1 * bf_lo(u1); acc1 += w1 * bf_hi(u1);
    }
    for (; e < cn; e += 2) {
        int s0 = csr_src[start + e];
        float w0 = dinv[s0] * di;
        unsigned u0 = xw[(size_t)s0 * 32 + sl];
        acc0 += w0 * bf_lo(u0); acc1 += w0 * bf_hi(u0);
    }
    acc0 += __shfl_xor(acc0, 32);
    acc1 += __shfl_xor(acc1, 32);
    if (h == 0) {
        float2 b = *(const float2*)&bias[2 * sl];
        *(float2*)&out[(size_t)i * 64 + 2 * sl] = make_float2(acc0 + b.x, acc1 + b.y);
    }
}

// In-place log_softmax over 64 cols; one wave per row.
__global__ void k_lsm(float* __restrict__ out, int N) {
    const int lane = threadIdx.x & 63;
    const int row = (blockIdx.x * blockDim.x + threadIdx.x) >> 6;
    if (row >= N) return;
    float v = out[(size_t)row * 64 + lane];
    float m = v;
#pragma unroll
    for (int o = 32; o > 0; o >>= 1) m = fmaxf(m, __shfl_xor(m, o));
    float e = expf(v - m);
    float s = e;
#pragma unroll
    for (int o = 32; o > 0; o >>= 1) s += __shfl_xor(s, o);
    out[(size_t)row * 64 + lane] = v - m - logf(s);
}

extern "C" void kernel_launch(void* const* d_in, const int* in_sizes, int n_in,
                              void* d_out, int out_size, void* d_ws, size_t ws_size,
                              hipStream_t stream) {
    const float* x  = (const float*)d_in[0];
    const int*   ei = (const int*)d_in[1];
    const float* W1 = (const float*)d_in[2];
    const float* b1 = (const float*)d_in[3];
    const float* W2 = (const float*)d_in[4];
    const float* b2 = (const float*)d_in[5];

    const int N = in_sizes[0] / 128;   // 100000
    const int E = in_sizes[1] / 2;     // 1600000
    const int* src = ei;
    const int* dst = ei + E;
    const int B = (N + 255) >> BSHIFT; // 391 buckets

    char* ws = (char*)d_ws;
    size_t off = 0;
    auto alloc = [&](size_t bytes) {
        void* p = ws + off;
        off += (bytes + 255) & ~(size_t)255;
        return p;
    };
    int*            bcnt    = (int*)alloc(MAXB * 4 * 2);    // bcnt + bfill adjacent
    int*            bfill   = bcnt + MAXB;
    int*            boff    = (int*)alloc((MAXB + 1) * 4);
    int*            deg     = (int*)alloc((size_t)N * 4);
    float*          dinv    = (float*)alloc((size_t)N * 4);
    int*            rowptr  = (int*)alloc((size_t)N * 4);
    int*            csr_src = (int*)alloc((size_t)E * 4);
    uint2*          pairs   = (uint2*)alloc((size_t)E * 8);
    unsigned short* Wt1     = (unsigned short*)alloc(128 * 128 * 2);
    unsigned short* Wt2     = (unsigned short*)alloc(64 * 128 * 2);
    unsigned short* xw1     = (unsigned short*)alloc((size_t)N * 128 * 2);  // bf16; reused as hw2
    unsigned short* h1      = (unsigned short*)alloc((size_t)N * 128 * 2);  // bf16
    unsigned short* hw2     = xw1;
    float*          out     = (float*)d_out;

    hipMemsetAsync(bcnt, 0, MAXB * 4 * 2, stream);

    // CSR build (bucketed, XCD-local)
    k_bcount<<<512, THREADS, 0, stream>>>(dst, E, B, bcnt);
    k_bscan<<<1, MAXB, 0, stream>>>(bcnt, B, boff);
    k_bscatter<<<(E + 8191) / 8192, THREADS, 0, stream>>>(src, dst, E, B, boff, bfill, pairs);
    k_bbuild<<<B, THREADS, 0, stream>>>(pairs, boff, N, deg, dinv, rowptr, csr_src);

    k_castW<<<96, THREADS, 0, stream>>>(W1, W2, Wt1, Wt2);

    // Layer 1
    k_gemm_mfma<128, false><<<(N + 63) / 64, THREADS, 0, stream>>>(x, Wt1, xw1, N);
    k_agg128b<<<(N * 64 + THREADS - 1) / THREADS, THREADS, 0, stream>>>(
        csr_src, rowptr, deg, dinv, (const unsigned*)xw1, b1, (unsigned*)h1, N);

    // Layer 2
    k_gemm_mfma<64, true><<<(N + 63) / 64, THREADS, 0, stream>>>(h1, Wt2, hw2, N);
    k_agg64b<<<(N * 64 + THREADS - 1) / THREADS, THREADS, 0, stream>>>(
        csr_src, rowptr, deg, dinv, (const unsigned*)hw2, b2, out, N);

    k_lsm<<<(N * 64 + THREADS - 1) / THREADS, THREADS, 0, stream>>>(out, N);
}

// Round 5
// 327.364 us; speedup vs baseline: 3.9212x; 1.0642x over previous
//
#include <hip/hip_runtime.h>
#include <cmath>

// GCN 2-layer forward on MI355X — round 5: deep-unrolled gathers (MLP), fused lsm,
// packed 4B pair records in the CSR build.
// Pipeline: bcount -> bscan -> bscatter(packed) -> bbuild ->
//           gemm1_mfma(x@W1 -> bf16) -> agg128 (unroll8, bias+selfloop+relu -> bf16 h1) ->
//           gemm2_mfma(h1@W2 -> bf16) -> agg64+log_softmax fused -> done.

#define THREADS 256
#define BSHIFT 8                      // 256 nodes per bucket
#define MAXB 512                      // >= ceil(N / 256)

__device__ __forceinline__ unsigned short f2bf(float f) {
    union { float f; unsigned u; } v; v.f = f;
    unsigned r = v.u + 0x7FFFu + ((v.u >> 16) & 1u);   // round-nearest-even
    return (unsigned short)(r >> 16);
}
__device__ __forceinline__ float bf_lo(unsigned u) {
    union { unsigned u; float f; } v; v.u = u << 16; return v.f;
}
__device__ __forceinline__ float bf_hi(unsigned u) {
    union { unsigned u; float f; } v; v.u = u & 0xFFFF0000u; return v.f;
}

// ---- bucket count: LDS histogram, flush once per block ----
__global__ __launch_bounds__(256) void k_bcount(const int* __restrict__ dst, int E, int B,
                                                int* __restrict__ bcnt) {
    __shared__ int lc[MAXB];
    for (int i = threadIdx.x; i < MAXB; i += 256) lc[i] = 0;
    __syncthreads();
    for (int e = blockIdx.x * blockDim.x + threadIdx.x; e < E; e += gridDim.x * blockDim.x)
        atomicAdd(&lc[dst[e] >> BSHIFT], 1);
    __syncthreads();
    for (int b = threadIdx.x; b < B; b += 256)
        if (lc[b]) atomicAdd(&bcnt[b], lc[b]);
}

// ---- exclusive scan of bcnt[B] -> boff[B+1], single block of 512 ----
__global__ void k_bscan(const int* __restrict__ bcnt, int B, int* __restrict__ boff) {
    __shared__ int sh[MAXB];
    const int t = threadIdx.x;
    int v = (t < B) ? bcnt[t] : 0;
    sh[t] = v; __syncthreads();
    for (int o = 1; o < MAXB; o <<= 1) {
        int add = (t >= o) ? sh[t - o] : 0;
        __syncthreads();
        sh[t] += add;
        __syncthreads();
    }
    if (t < B) boff[t] = sh[t] - v;
    if (t == B - 1) boff[B] = sh[t];
}

// ---- scatter edges into bucket-contiguous packed records (loc<<24 | src) ----
__global__ __launch_bounds__(256) void k_bscatter(const int* __restrict__ src,
                                                  const int* __restrict__ dst, int E, int B,
                                                  const int* __restrict__ boff,
                                                  int* __restrict__ bfill,
                                                  unsigned* __restrict__ pairs) {
    __shared__ int lc[MAXB];     // per-block bucket count, then per-bucket rank
    __shared__ int lbase[MAXB];  // global reservation base within bucket
    const int tid = threadIdx.x;
    const int e0 = blockIdx.x * 8192;
    for (int i = tid; i < MAXB; i += 256) lc[i] = 0;
    __syncthreads();
#pragma unroll
    for (int k = 0; k < 32; k++) {
        int e = e0 + k * 256 + tid;
        if (e < E) atomicAdd(&lc[dst[e] >> BSHIFT], 1);
    }
    __syncthreads();
    for (int b = tid; b < B; b += 256)
        lbase[b] = lc[b] ? atomicAdd(&bfill[b], lc[b]) : 0;
    __syncthreads();
    for (int i = tid; i < MAXB; i += 256) lc[i] = 0;  // reuse as rank
    __syncthreads();
#pragma unroll
    for (int k = 0; k < 32; k++) {
        int e = e0 + k * 256 + tid;
        if (e < E) {
            int s = src[e], d = dst[e];
            int b = d >> BSHIFT;
            int r = atomicAdd(&lc[b], 1);
            pairs[(size_t)boff[b] + lbase[b] + r] =
                ((unsigned)(d & 255) << 24) | (unsigned)s;   // src < 2^24
        }
    }
}

// ---- per-bucket CSR build: one block per bucket; all scatter is XCD-local ----
__global__ __launch_bounds__(256) void k_bbuild(const unsigned* __restrict__ pairs,
                                                const int* __restrict__ boff, int N,
                                                int* __restrict__ deg,
                                                float* __restrict__ dinv,
                                                int* __restrict__ rowptr,
                                                int* __restrict__ csr_src) {
    __shared__ int ldeg[256], lex[256], lrank[256];
    const int b = blockIdx.x, tid = threadIdx.x;
    const int node0 = b << BSHIFT;
    const int base = boff[b];
    const int cnt_e = boff[b + 1] - base;
    ldeg[tid] = 0;
    __syncthreads();
    for (int e = tid; e < cnt_e; e += 256)
        atomicAdd(&ldeg[pairs[base + e] >> 24], 1);
    __syncthreads();
    int v = ldeg[tid];
    lex[tid] = v; __syncthreads();
    for (int o = 1; o < 256; o <<= 1) {
        int add = (tid >= o) ? lex[tid - o] : 0;
        __syncthreads();
        lex[tid] += add;
        __syncthreads();
    }
    int excl = lex[tid] - v;
    if (node0 + tid < N) {
        deg[node0 + tid] = v;
        dinv[node0 + tid] = rsqrtf((float)(v + 1));
        rowptr[node0 + tid] = base + excl;
    }
    __syncthreads();
    lex[tid] = excl;       // keep exclusive offsets
    lrank[tid] = 0;
    __syncthreads();
    for (int e = tid; e < cnt_e; e += 256) {
        unsigned p = pairs[base + e];
        int loc = p >> 24;
        int r = atomicAdd(&lrank[loc], 1);
        csr_src[base + lex[loc] + r] = (int)(p & 0xFFFFFFu);
    }
}

// Wt1[n][k] = bf16(W1[k][n]) (128x128), Wt2[n][k] = bf16(W2[k][n]) (64x128)
__global__ void k_castW(const float* __restrict__ W1, const float* __restrict__ W2,
                        unsigned short* __restrict__ Wt1, unsigned short* __restrict__ Wt2) {
    int idx = blockIdx.x * blockDim.x + threadIdx.x;
    if (idx < 16384) {
        int n = idx >> 7, k = idx & 127;
        Wt1[idx] = f2bf(W1[k * 128 + n]);
    } else if (idx < 16384 + 8192) {
        int t = idx - 16384;
        int n = t >> 7, k = t & 127;
        Wt2[t] = f2bf(W2[k * 64 + n]);
    }
}

// C[M x NC](bf16) = A[M x 128] @ Wt^T, Wt is [NC x 128] bf16 (pre-transposed W).
typedef __attribute__((ext_vector_type(8))) short bf16x8;
typedef __attribute__((ext_vector_type(4))) float f32x4;

template <int NC, bool A_BF16>
__global__ __launch_bounds__(256) void k_gemm_mfma(const void* __restrict__ Av,
                                                   const unsigned short* __restrict__ Wt,
                                                   unsigned short* __restrict__ Out, int M) {
    constexpr int KP = 136;                 // padded k-stride
    __shared__ __align__(16) short As[64 * KP];
    __shared__ __align__(16) short Bs[NC * KP];
    const int tid = threadIdx.x;
    const int row0 = blockIdx.x * 64;

    if (A_BF16) {
        const unsigned short* A = (const unsigned short*)Av;
#pragma unroll
        for (int q = 0; q < 4; q++) {
            int f = tid + 256 * q;
            int r = f >> 4, c = (f & 15) * 8;
            uint4 v = make_uint4(0, 0, 0, 0);
            if (row0 + r < M) v = *(const uint4*)&A[(size_t)(row0 + r) * 128 + c];
            *(uint4*)&As[r * KP + c] = v;
        }
    } else {
        const float* A = (const float*)Av;
#pragma unroll
        for (int q = 0; q < 8; q++) {
            int f = tid + 256 * q;
            int r = f >> 5, c = (f & 31) * 4;
            float4 v = make_float4(0.f, 0.f, 0.f, 0.f);
            if (row0 + r < M) v = *(const float4*)&A[(size_t)(row0 + r) * 128 + c];
            ushort4 o;
            o.x = f2bf(v.x); o.y = f2bf(v.y); o.z = f2bf(v.z); o.w = f2bf(v.w);
            *(ushort4*)&As[r * KP + c] = o;
        }
    }
    for (int f = tid; f < NC * 16; f += 256) {
        int n = f >> 4, c = (f & 15) * 8;
        *(uint4*)&Bs[n * KP + c] = *(const uint4*)&Wt[n * 128 + c];
    }
    __syncthreads();

    const int wave = tid >> 6, lane = tid & 63;
    const int m = lane & 15, quad = lane >> 4;
    constexpr int CT = NC / 16;
    f32x4 acc[CT] = {};
    const short* arow = &As[(16 * wave + m) * KP + quad * 8];
    const short* brow = &Bs[m * KP + quad * 8];
#pragma unroll
    for (int k0 = 0; k0 < 128; k0 += 32) {
        bf16x8 a = *(const bf16x8*)&arow[k0];
#pragma unroll
        for (int c = 0; c < CT; c++) {
            bf16x8 b = *(const bf16x8*)&brow[(size_t)c * 16 * KP + k0];
            acc[c] = __builtin_amdgcn_mfma_f32_16x16x32_bf16(a, b, acc[c], 0, 0, 0);
        }
    }

    __syncthreads();
    short* Cs = As;
#pragma unroll
    for (int c = 0; c < CT; c++)
#pragma unroll
        for (int r = 0; r < 4; r++)
            Cs[(16 * wave + quad * 4 + r) * NC + 16 * c + m] = (short)f2bf(acc[c][r]);
    __syncthreads();
    for (int f = tid; f < 64 * NC / 8; f += 256) {
        int r = f / (NC / 8), c = (f % (NC / 8)) * 8;
        if (row0 + r < M)
            *(uint4*)&Out[(size_t)(row0 + r) * NC + c] = *(const uint4*)&Cs[r * NC + c];
    }
}

// Aggregate 128-wide bf16 rows. One wave per node; lane covers cols {2l, 2l+1}.
// 8-deep unroll for memory-level parallelism (8 row-gathers in flight).
__global__ __launch_bounds__(256) void k_agg128b(const int* __restrict__ csr_src,
                                                 const int* __restrict__ rowptr,
                                                 const int* __restrict__ cnt,
                                                 const float* __restrict__ dinv,
                                                 const unsigned* __restrict__ xw,
                                                 const float* __restrict__ bias,
                                                 unsigned* __restrict__ h1, int N) {
    const int lane = threadIdx.x & 63;
    const int i = (blockIdx.x * blockDim.x + threadIdx.x) >> 6;
    if (i >= N) return;
    const float di = dinv[i];
    unsigned u = xw[(size_t)i * 64 + lane];
    float acc0 = di * di * bf_lo(u);
    float acc1 = di * di * bf_hi(u);
    const int start = rowptr[i], cn = cnt[i];
    int j = 0;
    for (; j + 8 <= cn; j += 8) {
        int s[8]; unsigned uu[8]; float w[8];
#pragma unroll
        for (int k = 0; k < 8; k++) s[k] = csr_src[start + j + k];   // wave-uniform -> s_load
#pragma unroll
        for (int k = 0; k < 8; k++) uu[k] = xw[(size_t)s[k] * 64 + lane];
#pragma unroll
        for (int k = 0; k < 8; k++) w[k] = dinv[s[k]] * di;
#pragma unroll
        for (int k = 0; k < 8; k++) {
            acc0 += w[k] * bf_lo(uu[k]);
            acc1 += w[k] * bf_hi(uu[k]);
        }
    }
    for (; j < cn; j++) {
        int s0 = csr_src[start + j];
        float w0 = dinv[s0] * di;
        unsigned u0 = xw[(size_t)s0 * 64 + lane];
        acc0 += w0 * bf_lo(u0); acc1 += w0 * bf_hi(u0);
    }
    float2 b = *(const float2*)&bias[2 * lane];
    float r0 = fmaxf(acc0 + b.x, 0.f);    // ReLU folded (layer-1 epilogue)
    float r1 = fmaxf(acc1 + b.y, 0.f);
    h1[(size_t)i * 64 + lane] = (unsigned)f2bf(r0) | ((unsigned)f2bf(r1) << 16);
}

// Aggregate 64-wide bf16 rows; half-wave per edge stream, 4-deep unroll per half
// (8 gathers in flight per wave). log_softmax fused into the epilogue.
__global__ __launch_bounds__(256) void k_agg64b(const int* __restrict__ csr_src,
                                                const int* __restrict__ rowptr,
                                                const int* __restrict__ cnt,
                                                const float* __restrict__ dinv,
                                                const unsigned* __restrict__ xw,
                                                const float* __restrict__ bias,
                                                float* __restrict__ out, int N) {
    const int lane = threadIdx.x & 63;
    const int i = (blockIdx.x * blockDim.x + threadIdx.x) >> 6;
    if (i >= N) return;
    const int h = lane >> 5, sl = lane & 31;
    const float di = dinv[i];
    float acc0 = 0.f, acc1 = 0.f;
    if (h == 0) {
        unsigned u = xw[(size_t)i * 32 + sl];
        acc0 = di * di * bf_lo(u);
        acc1 = di * di * bf_hi(u);
    }
    const int start = rowptr[i], cn = cnt[i];
    int e = h;
    for (; e + 6 < cn; e += 8) {          // each half: edges e, e+2, e+4, e+6
        int s[4]; unsigned uu[4]; float w[4];
#pragma unroll
        for (int k = 0; k < 4; k++) s[k] = csr_src[start + e + 2 * k];
#pragma unroll
        for (int k = 0; k < 4; k++) uu[k] = xw[(size_t)s[k] * 32 + sl];
#pragma unroll
        for (int k = 0; k < 4; k++) w[k] = dinv[s[k]] * di;
#pragma unroll
        for (int k = 0; k < 4; k++) {
            acc0 += w[k] * bf_lo(uu[k]);
            acc1 += w[k] * bf_hi(uu[k]);
        }
    }
    for (; e < cn; e += 2) {
        int s0 = csr_src[start + e];
        float w0 = dinv[s0] * di;
        unsigned u0 = xw[(size_t)s0 * 32 + sl];
        acc0 += w0 * bf_lo(u0); acc1 += w0 * bf_hi(u0);
    }
    acc0 += __shfl_xor(acc0, 32);         // both halves now hold full sums
    acc1 += __shfl_xor(acc1, 32);
    float2 b = *(const float2*)&bias[2 * sl];
    float v0 = acc0 + b.x, v1 = acc1 + b.y;
    // fused log_softmax over 64 cols (2 per lane, duplicated across halves)
    float m = fmaxf(v0, v1);
#pragma unroll
    for (int o = 16; o > 0; o >>= 1) m = fmaxf(m, __shfl_xor(m, o));
    float s2 = expf(v0 - m) + expf(v1 - m);
#pragma unroll
    for (int o = 16; o > 0; o >>= 1) s2 += __shfl_xor(s2, o);
    float ls = m + logf(s2);
    if (h == 0)
        *(float2*)&out[(size_t)i * 64 + 2 * sl] = make_float2(v0 - ls, v1 - ls);
}

extern "C" void kernel_launch(void* const* d_in, const int* in_sizes, int n_in,
                              void* d_out, int out_size, void* d_ws, size_t ws_size,
                              hipStream_t stream) {
    const float* x  = (const float*)d_in[0];
    const int*   ei = (const int*)d_in[1];
    const float* W1 = (const float*)d_in[2];
    const float* b1 = (const float*)d_in[3];
    const float* W2 = (const float*)d_in[4];
    const float* b2 = (const float*)d_in[5];

    const int N = in_sizes[0] / 128;   // 100000
    const int E = in_sizes[1] / 2;     // 1600000
    const int* src = ei;
    const int* dst = ei + E;
    const int B = (N + 255) >> BSHIFT; // 391 buckets

    char* ws = (char*)d_ws;
    size_t off = 0;
    auto alloc = [&](size_t bytes) {
        void* p = ws + off;
        off += (bytes + 255) & ~(size_t)255;
        return p;
    };
    int*            bcnt    = (int*)alloc(MAXB * 4 * 2);    // bcnt + bfill adjacent
    int*            bfill   = bcnt + MAXB;
    int*            boff    = (int*)alloc((MAXB + 1) * 4);
    int*            deg     = (int*)alloc((size_t)N * 4);
    float*          dinv    = (float*)alloc((size_t)N * 4);
    int*            rowptr  = (int*)alloc((size_t)N * 4);
    int*            csr_src = (int*)alloc((size_t)E * 4);
    unsigned*       pairs   = (unsigned*)alloc((size_t)E * 4);
    unsigned short* Wt1     = (unsigned short*)alloc(128 * 128 * 2);
    unsigned short* Wt2     = (unsigned short*)alloc(64 * 128 * 2);
    unsigned short* xw1     = (unsigned short*)alloc((size_t)N * 128 * 2);  // bf16; reused as hw2
    unsigned short* h1      = (unsigned short*)alloc((size_t)N * 128 * 2);  // bf16
    unsigned short* hw2     = xw1;
    float*          out     = (float*)d_out;

    hipMemsetAsync(bcnt, 0, MAXB * 4 * 2, stream);

    // CSR build (bucketed, XCD-local)
    k_bcount<<<512, THREADS, 0, stream>>>(dst, E, B, bcnt);
    k_bscan<<<1, MAXB, 0, stream>>>(bcnt, B, boff);
    k_bscatter<<<(E + 8191) / 8192, THREADS, 0, stream>>>(src, dst, E, B, boff, bfill, pairs);
    k_bbuild<<<B, THREADS, 0, stream>>>(pairs, boff, N, deg, dinv, rowptr, csr_src);

    k_castW<<<96, THREADS, 0, stream>>>(W1, W2, Wt1, Wt2);

    // Layer 1
    k_gemm_mfma<128, false><<<(N + 63) / 64, THREADS, 0, stream>>>(x, Wt1, xw1, N);
    k_agg128b<<<(N * 64 + THREADS - 1) / THREADS, THREADS, 0, stream>>>(
        csr_src, rowptr, deg, dinv, (const unsigned*)xw1, b1, (unsigned*)h1, N);

    // Layer 2 (+ fused log_softmax)
    k_gemm_mfma<64, true><<<(N + 63) / 64, THREADS, 0, stream>>>(h1, Wt2, hw2, N);
    k_agg64b<<<(N * 64 + THREADS - 1) / THREADS, THREADS, 0, stream>>>(
        csr_src, rowptr, deg, dinv, (const unsigned*)hw2, b2, out, N);
}